// Round 3
// baseline (1272.182 us; speedup 1.0000x reference)
//
#include <hip/hip_runtime.h>
#include <cstdint>
#include <cstddef>

#define DEV __device__ __forceinline__

static constexpr float QEPS = 1e-5f;   // reference EPS
static constexpr int   MTOK = 8192;    // B*S tokens
static constexpr int   EMB  = 2048;    // N_EMBD
static constexpr int   DFF  = 8192;    // 4*N_EMBD
static constexpr int   MCH  = 2048;    // M-chunk rows for fp32-H staging in d_out

using bf16 = __bf16;
typedef __attribute__((ext_vector_type(8))) __bf16 bf16x8;
typedef __attribute__((ext_vector_type(4))) float  f32x4;

// async 16B global->LDS (generic -> AS1/AS3 addrspace casts).
DEV void async_cp16(const void* g, void* l) {
  __builtin_amdgcn_global_load_lds(
      (const __attribute__((address_space(1))) void*)g,
      (__attribute__((address_space(3))) void*)l, 16, 0, 0);
}

// Stage a 128x32 bf16 tile (row-major source, ldk elems/row) into LDS [128][32].
// Wave w covers 16 consecutive rows; lane l -> row w*16+(l>>2), col (l&3)*8,
// so LDS byte offset = wave_base + lane*16 (HW requirement for global_load_lds).
DEV void stage_tile(const bf16* __restrict__ g, int ldk, bf16* lds, int tid) {
  const int w  = tid >> 6, l = tid & 63;
  const int rr = l >> 2;
  const int cc = (l & 3) * 8;
#pragma unroll
  for (int it = 0; it < 2; ++it) {
    const int r = it * 64 + w * 16 + rr;
    async_cp16(g + (size_t)r * ldk + cc, lds + r * 32 + cc);
  }
}

// block-wide (256 thr) reduce: ss = sum, am = max. All threads get results.
DEV void block_reduce2(float& ss, float& am) {
#pragma unroll
  for (int off = 32; off > 0; off >>= 1) {
    ss += __shfl_down(ss, off);
    am  = fmaxf(am, __shfl_down(am, off));
  }
  __shared__ float s4[4], m4[4];
  const int w = threadIdx.x >> 6;
  if ((threadIdx.x & 63) == 0) { s4[w] = ss; m4[w] = am; }
  __syncthreads();
  ss = s4[0] + s4[1] + s4[2] + s4[3];
  am = fmaxf(fmaxf(m4[0], m4[1]), fmaxf(m4[2], m4[3]));
}

// ---------------- per-tensor sum(|w|) ----------------
__global__ __launch_bounds__(256) void absmean_partial_kernel(
    const float* __restrict__ w, size_t n4, float* __restrict__ out) {
  const float4* w4 = (const float4*)w;
  float s = 0.f;
  const size_t stride = (size_t)gridDim.x * blockDim.x;
  for (size_t i = (size_t)blockIdx.x * blockDim.x + threadIdx.x; i < n4; i += stride) {
    float4 v = w4[i];
    s += fabsf(v.x) + fabsf(v.y) + fabsf(v.z) + fabsf(v.w);
  }
#pragma unroll
  for (int off = 32; off > 0; off >>= 1) s += __shfl_down(s, off);
  __shared__ float s4[4];
  if ((threadIdx.x & 63) == 0) s4[threadIdx.x >> 6] = s;
  __syncthreads();
  if (threadIdx.x == 0) atomicAdd(out, s4[0] + s4[1] + s4[2] + s4[3]);
}

// ---------------- ternary weight quant -> bf16 INTEGER {-1,0,1} ----------------
__global__ __launch_bounds__(256) void quant_w_kernel(
    const float* __restrict__ w, bf16* __restrict__ wq,
    const float* __restrict__ sum, float inv_n, size_t n4) {
  const float mean = *sum * inv_n;
  const float sc   = 1.0f / fmaxf(mean, QEPS);
  const float4* w4 = (const float4*)w;
  ushort4* o4 = (ushort4*)wq;
  const size_t stride = (size_t)gridDim.x * blockDim.x;
  for (size_t i = (size_t)blockIdx.x * blockDim.x + threadIdx.x; i < n4; i += stride) {
    float4 v = w4[i];
    union { ushort4 u; __bf16 h[4]; } p;
    p.h[0] = (__bf16)fminf(fmaxf(rintf(v.x * sc), -1.f), 1.f);
    p.h[1] = (__bf16)fminf(fmaxf(rintf(v.y * sc), -1.f), 1.f);
    p.h[2] = (__bf16)fminf(fmaxf(rintf(v.z * sc), -1.f), 1.f);
    p.h[3] = (__bf16)fminf(fmaxf(rintf(v.w * sc), -1.f), 1.f);
    o4[i] = p.u;
  }
}

// ---------------- rmsnorm + absmax-quant of x rows (2048) -> integer bf16 + scale
__global__ __launch_bounds__(256) void rms_quant_x_kernel(
    const float* __restrict__ x, bf16* __restrict__ xq, float* __restrict__ s_out) {
  const size_t row = blockIdx.x;
  const float* xr = x + row * EMB;
  const int t = threadIdx.x;
  float4 v0 = ((const float4*)xr)[t];
  float4 v1 = ((const float4*)xr)[t + 256];
  float vals[8] = {v0.x, v0.y, v0.z, v0.w, v1.x, v1.y, v1.z, v1.w};
  float ss = 0.f, am = 0.f;
#pragma unroll
  for (int i = 0; i < 8; ++i) { ss += vals[i] * vals[i]; am = fmaxf(am, fabsf(vals[i])); }
  block_reduce2(ss, am);
  const float r = rsqrtf(ss * (1.0f / (float)EMB) + 1e-6f);
  const float s = 127.0f / fmaxf(am * r, QEPS);
  union { ushort4 u; __bf16 h[4]; } p0, p1;
#pragma unroll
  for (int i = 0; i < 4; ++i) {
    float q0 = fminf(fmaxf(rintf((vals[i]     * r) * s), -128.f), 127.f);
    float q1 = fminf(fmaxf(rintf((vals[4 + i] * r) * s), -128.f), 127.f);
    p0.h[i] = (__bf16)q0;
    p1.h[i] = (__bf16)q1;
  }
  ushort4* qr = (ushort4*)(xq + row * EMB);
  qr[t]       = p0.u;
  qr[t + 256] = p1.u;
  if (t == 0) s_out[row] = s;
}

// ---------------- rmsnorm + absmax-quant of fp32 H rows (8192) -> int8 + scale
__global__ __launch_bounds__(256) void rms_quant_h_kernel(
    const float* __restrict__ H, signed char* __restrict__ hq,
    float* __restrict__ s_out) {
  const size_t row = blockIdx.x;
  const float* hr = H + row * (size_t)DFF;
  const int t = threadIdx.x;
  float vals[32];
#pragma unroll
  for (int k = 0; k < 8; ++k) {
    float4 v = ((const float4*)hr)[t + k * 256];
    vals[k * 4 + 0] = v.x; vals[k * 4 + 1] = v.y;
    vals[k * 4 + 2] = v.z; vals[k * 4 + 3] = v.w;
  }
  float ss = 0.f, am = 0.f;
#pragma unroll
  for (int i = 0; i < 32; ++i) { ss += vals[i] * vals[i]; am = fmaxf(am, fabsf(vals[i])); }
  block_reduce2(ss, am);
  const float r = rsqrtf(ss * (1.0f / (float)DFF) + 1e-6f);
  const float s = 127.0f / fmaxf(am * r, QEPS);
  int* qrow = (int*)(hq + row * (size_t)DFF);
#pragma unroll
  for (int k = 0; k < 8; ++k) {
    union { int i; signed char c[4]; } p;
#pragma unroll
    for (int j = 0; j < 4; ++j) {
      float q = fminf(fmaxf(rintf(vals[k * 4 + j] * r * s), -128.f), 127.f);
      p.c[j] = (signed char)(int)q;
    }
    qrow[t + k * 256] = p.i;
  }
  if (t == 0) s_out[row] = s;
}

// ---------------- dual GEMM (C1 = Xq*W1^T, C2 = Xq*W2^T), silu(C1)*C2 -> H (fp32)
// M fixed = MCH (one chunk). Integer-exact MFMA; scales folded in epilogue.
__global__ __launch_bounds__(256, 2) void dual_gemm_silu_kernel(
    const bf16* __restrict__ Xq, const bf16* __restrict__ W1,
    const bf16* __restrict__ W2, float* __restrict__ H,
    const float* __restrict__ s_x, const float* __restrict__ wsum, float inv_nw) {
  __shared__ alignas(16) bf16 sA[128 * 32];
  __shared__ alignas(16) bf16 sB1[128 * 32];
  __shared__ alignas(16) bf16 sB2[128 * 32];
  const int tid = threadIdx.x;
  const int lane = tid & 63, wv = tid >> 6;
  const int wm = (wv >> 1) * 64, wn = (wv & 1) * 64;
  const int bm = blockIdx.y * 128, bn = blockIdx.x * 128;
  const int fr = lane & 15, fq = lane >> 4;

  f32x4 acc1[4][4] = {}, acc2[4][4] = {};

  for (int k0 = 0; k0 < EMB; k0 += 32) {
    stage_tile(Xq + (size_t)bm * EMB + k0, EMB, sA, tid);
    stage_tile(W1 + (size_t)bn * EMB + k0, EMB, sB1, tid);
    stage_tile(W2 + (size_t)bn * EMB + k0, EMB, sB2, tid);
    __syncthreads();
    bf16x8 af[4], b1[4], b2[4];
#pragma unroll
    for (int i = 0; i < 4; ++i)
      af[i] = *(const bf16x8*)&sA[(wm + i * 16 + fr) * 32 + fq * 8];
#pragma unroll
    for (int j = 0; j < 4; ++j) {
      b1[j] = *(const bf16x8*)&sB1[(wn + j * 16 + fr) * 32 + fq * 8];
      b2[j] = *(const bf16x8*)&sB2[(wn + j * 16 + fr) * 32 + fq * 8];
    }
#pragma unroll
    for (int i = 0; i < 4; ++i)
#pragma unroll
      for (int j = 0; j < 4; ++j) {
        acc1[i][j] = __builtin_amdgcn_mfma_f32_16x16x32_bf16(af[i], b1[j], acc1[i][j], 0, 0, 0);
        acc2[i][j] = __builtin_amdgcn_mfma_f32_16x16x32_bf16(af[i], b2[j], acc2[i][j], 0, 0, 0);
      }
    __syncthreads();
  }

  const float sw1 = 1.0f / fmaxf(wsum[0] * inv_nw, QEPS);
  const float sw2 = 1.0f / fmaxf(wsum[1] * inv_nw, QEPS);
#pragma unroll
  for (int i = 0; i < 4; ++i) {
#pragma unroll
    for (int r = 0; r < 4; ++r) {
      const int m = bm + wm + i * 16 + fq * 4 + r;   // row within chunk
      const float d1 = s_x[m] * sw1;
      const float d2 = s_x[m] * sw2;
#pragma unroll
      for (int j = 0; j < 4; ++j) {
        const float t1 = acc1[i][j][r] / d1;
        const float t2 = acc2[i][j][r] / d2;
        const float hv = (t1 / (1.0f + expf(-t1))) * t2;
        H[(size_t)m * DFF + (bn + wn + j * 16 + fr)] = hv;
      }
    }
  }
}

// ---------------- GEMM3: out = (Hq(int8) * Wq3^T(bf16)) / (s_h[m] * sw3), fp32 out
// A staged int8 -> bf16 via registers into padded LDS; B staged async bf16.
__global__ __launch_bounds__(256, 2) void gemm_out_kernel(
    const signed char* __restrict__ Aq, const bf16* __restrict__ B,
    float* __restrict__ C, const float* __restrict__ s_a,
    const float* __restrict__ wsum2, float inv_nw) {
  constexpr int LDA = 40;                       // padded A row (breaks conflicts)
  __shared__ alignas(16) bf16 sA[128 * LDA];
  __shared__ alignas(16) bf16 sB[128 * 32];
  const int tid = threadIdx.x;
  const int lane = tid & 63, wv = tid >> 6;
  const int wm = (wv >> 1) * 64, wn = (wv & 1) * 64;
  const int bm = blockIdx.y * 128, bn = blockIdx.x * 128;
  const int fr = lane & 15, fq = lane >> 4;
  const int arow = tid >> 1, ahalf = (tid & 1) << 4;   // A-staging: 2 thr/row

  f32x4 acc[4][4] = {};

  for (int k0 = 0; k0 < DFF; k0 += 32) {
    // A: load 16 int8, convert to bf16, write 32B to padded LDS
    union { int4 v; signed char c[16]; } u;
    u.v = *(const int4*)(Aq + (size_t)(bm + arow) * DFF + k0 + ahalf);
    bf16x8 p0, p1;
#pragma unroll
    for (int j = 0; j < 8; ++j) {
      p0[j] = (__bf16)(float)u.c[j];
      p1[j] = (__bf16)(float)u.c[8 + j];
    }
    *(bf16x8*)&sA[arow * LDA + ahalf] = p0;
    *(bf16x8*)&sA[arow * LDA + ahalf + 8] = p1;
    // B: async 16B global->LDS
    stage_tile(B + (size_t)bn * DFF + k0, DFF, sB, tid);
    __syncthreads();
    bf16x8 af[4], bb[4];
#pragma unroll
    for (int i = 0; i < 4; ++i)
      af[i] = *(const bf16x8*)&sA[(wm + i * 16 + fr) * LDA + fq * 8];
#pragma unroll
    for (int j = 0; j < 4; ++j)
      bb[j] = *(const bf16x8*)&sB[(wn + j * 16 + fr) * 32 + fq * 8];
#pragma unroll
    for (int i = 0; i < 4; ++i)
#pragma unroll
      for (int j = 0; j < 4; ++j)
        acc[i][j] = __builtin_amdgcn_mfma_f32_16x16x32_bf16(af[i], bb[j], acc[i][j], 0, 0, 0);
    __syncthreads();
  }

  const float sw = 1.0f / fmaxf(wsum2[0] * inv_nw, QEPS);
#pragma unroll
  for (int i = 0; i < 4; ++i) {
#pragma unroll
    for (int r = 0; r < 4; ++r) {
      const int m = bm + wm + i * 16 + fq * 4 + r;
      const float d = s_a[m] * sw;
#pragma unroll
      for (int j = 0; j < 4; ++j)
        C[(size_t)m * EMB + (bn + wn + j * 16 + fr)] = acc[i][j][r] / d;
    }
  }
}

extern "C" void kernel_launch(void* const* d_in, const int* in_sizes, int n_in,
                              void* d_out, int out_size, void* d_ws, size_t ws_size,
                              hipStream_t stream) {
  const float* x  = (const float*)d_in[0];
  const float* w1 = (const float*)d_in[1];
  const float* w2 = (const float*)d_in[2];
  const float* w3 = (const float*)d_in[3];
  float* out = (float*)d_out;

  const size_t NW = (size_t)DFF * EMB;       // 16,777,216 elems per weight
  const float inv_nw = 1.0f / (float)NW;
  const size_t MB = 1ull << 20;

  // ---- scratch layout (d_ws use: 161 MB) ----
  // header [0,1MB): wsum, s_x, s_h
  // xq  bf16 [  1, 33)MB   | wq1 bf16 [33,65)MB (wq3 overlays after dual GEMM)
  // wq2 bf16 [ 65, 97)MB   | hq int8 [97,161)MB
  // H fp32 chunk (2048 x 8192 = 64MB) lives in d_out until GEMM3 overwrites it.
  char* ws = (char*)d_ws;
  float* wsum = (float*)ws;                  // 3 partial-sum floats
  float* s_x  = (float*)(ws + 4096);         // 8192 floats
  float* s_h  = (float*)(ws + 4096 + 32768); // 8192 floats
  bf16* xq  = (bf16*)(ws + MB);
  bf16* wq1 = (bf16*)(ws + 33 * MB);
  bf16* wq3 = wq1;                           // overlay (wq1 dead after dual GEMM)
  bf16* wq2 = (bf16*)(ws + 65 * MB);
  signed char* hq = (signed char*)(ws + 97 * MB);
  float* H = (float*)d_out;                  // fp32 H chunk buffer

  hipMemsetAsync(wsum, 0, 256, stream);
  absmean_partial_kernel<<<1024, 256, 0, stream>>>(w1, NW / 4, wsum + 0);
  absmean_partial_kernel<<<1024, 256, 0, stream>>>(w2, NW / 4, wsum + 1);
  absmean_partial_kernel<<<1024, 256, 0, stream>>>(w3, NW / 4, wsum + 2);
  quant_w_kernel<<<1024, 256, 0, stream>>>(w1, wq1, wsum + 0, inv_nw, NW / 4);
  quant_w_kernel<<<1024, 256, 0, stream>>>(w2, wq2, wsum + 1, inv_nw, NW / 4);
  rms_quant_x_kernel<<<MTOK, 256, 0, stream>>>(x, xq, s_x);

  for (int c = 0; c < MTOK / MCH; ++c) {
    dual_gemm_silu_kernel<<<dim3(DFF / 128, MCH / 128), 256, 0, stream>>>(
        xq + (size_t)c * MCH * EMB, wq1, wq2, H, s_x + c * MCH, wsum, inv_nw);
    rms_quant_h_kernel<<<MCH, 256, 0, stream>>>(
        H, hq + (size_t)c * MCH * DFF, s_h + c * MCH);
  }

  quant_w_kernel<<<1024, 256, 0, stream>>>(w3, wq3, wsum + 2, inv_nw, NW / 4);
  gemm_out_kernel<<<dim3(EMB / 128, MTOK / 128), 256, 0, stream>>>(
      hq, wq3, out, s_h, wsum + 2, inv_nw);
}